// Round 11
// baseline (30.996 us; speedup 1.0000x reference)
//
#include <hip/hip_runtime.h>

typedef short bf16x8 __attribute__((ext_vector_type(8)));
typedef float f32x4 __attribute__((ext_vector_type(4)));

#define TT 4096
#define CC 1024
#define HH 64
#define MTOT 16384   // B*T = 4*4096

static __device__ __forceinline__ unsigned short f2bf(float f) {
  unsigned int u = __float_as_uint(f);
  unsigned int r = (u + 0x7FFFu + ((u >> 16) & 1u)) >> 16;
  return (unsigned short)r;
}

// round-half-up f32 pair -> packed bf16x2 (1 add each + 1 perm)
static __device__ __forceinline__ unsigned int pack_bf2(float lo, float hi) {
  unsigned int ul = __float_as_uint(lo) + 0x8000u;
  unsigned int uh = __float_as_uint(hi) + 0x8000u;
  return __builtin_amdgcn_perm(uh, ul, 0x07060302u);  // [ul>>16, uh>>16]
}

typedef const __attribute__((address_space(1))) void gvoid;
typedef __attribute__((address_space(3))) void svoid;
static __device__ __forceinline__ void gll16(const void* g, void* l) {
  __builtin_amdgcn_global_load_lds((gvoid*)g, (svoid*)l, 16, 0, 0);
}

#define WAITVM(N) asm volatile("s_waitcnt vmcnt(" #N ")" ::: "memory")

// ---------------- kernel 0: W -> Wt[192][1024] bf16 (transposed, concat k|q|v)
__global__ void prep_wt(const float* __restrict__ Wk, const float* __restrict__ Wq,
                        const float* __restrict__ Wv, unsigned short* __restrict__ Wt) {
  __shared__ float T[64][65];
  const int mat = blockIdx.x >> 4;         // 0..2  (48 blocks)
  const int kt = blockIdx.x & 15;          // 0..15
  const float* src = (mat == 0) ? Wk : ((mat == 1) ? Wq : Wv);
#pragma unroll
  for (int i = 0; i < 4; ++i) {
    int c = i * 256 + threadIdx.x;         // 0..1023 f32x4 chunks
    int row = c >> 4, col = (c & 15) * 4;
    f32x4 v = *(const f32x4*)&src[(size_t)(kt * 64 + row) * HH + col];
    T[col + 0][row] = v[0];
    T[col + 1][row] = v[1];
    T[col + 2][row] = v[2];
    T[col + 3][row] = v[3];
  }
  __syncthreads();
#pragma unroll
  for (int i = 0; i < 2; ++i) {
    int c2 = i * 256 + threadIdx.x;        // 0..511 bf16x8 chunks
    int row = c2 >> 3, k0 = (c2 & 7) * 8;
    union { bf16x8 v; unsigned short h[8]; } pk;
#pragma unroll
    for (int j = 0; j < 8; ++j) pk.h[j] = f2bf(T[row][k0 + j]);
    *(bf16x8*)&Wt[(size_t)(mat * 64 + row) * CC + kt * 64 + k0] = pk.v;
  }
}

// ---------------- kernel 1: projections, DMA-only K-loop GEMM, BM=64
// R10 structure; ONE change: k/q epilogue routed through padded LDS (like V)
// -> fully-coalesced bf16x8 stores (was per-lane 2B scatter, 32B segments).
__global__ __launch_bounds__(512, 2) void proj_kernel(
    const float* __restrict__ x, const unsigned short* __restrict__ Wt,
    unsigned short* __restrict__ kb, unsigned short* __restrict__ qb,
    unsigned short* __restrict__ vt) {
  extern __shared__ __align__(16) char smem[];
  float* Xl = (float*)smem;                                   // [3][64*64] f32 = 48KB
  unsigned short* Bl = (unsigned short*)(smem + 49152);       // [3][192*64] bf16 = 72KB

  const int tid = threadIdx.x;
  const int lane = tid & 63;
  const int w = tid >> 6;                  // 0..7
  const int r = lane & 15, g = lane >> 4;
  const int rowgrp = w >> 1;               // 0..3 -> rows rowgrp*16..+15
  const int colbase = (w & 1) * 96;        // 0 or 96
  const int m0 = blockIdx.x * 64;

  // ---- staging sources (5 x 16B chunks per thread per tile), pre-swizzled
  const float* xsrcs[2];
#pragma unroll
  for (int j = 0; j < 2; ++j) {
    int c = j * 512 + tid;
    int row = c >> 4, s = c & 15;
    xsrcs[j] = x + (size_t)(m0 + row) * CC + (((s & 8) | ((s & 7) ^ (row & 7))) * 4);
  }
  const unsigned short* bsrcs[3];
#pragma unroll
  for (int j = 0; j < 3; ++j) {
    int cb = j * 512 + tid;
    int row = cb >> 3, s = cb & 7;
    bsrcs[j] = Wt + (size_t)row * CC + ((s ^ (row & 7)) * 8);
  }

  f32x4 acc[6];
#pragma unroll
  for (int n = 0; n < 6; ++n) { f32x4 z = {0.f, 0.f, 0.f, 0.f}; acc[n] = z; }

  auto stage = [&](int t, int buf) {
    float* xb = Xl + buf * 4096;
    unsigned short* bb = Bl + buf * 12288;
#pragma unroll
    for (int j = 0; j < 2; ++j)
      gll16(xsrcs[j] + t * 64, xb + (j * 512 + w * 64) * 4);
#pragma unroll
    for (int j = 0; j < 3; ++j)
      gll16(bsrcs[j] + t * 64, bb + (size_t)(j * 512 + w * 64) * 8);
  };

  const int rr = rowgrp * 16 + r;
  const int rb = rr * 64;
  const int rx = rr & 7;

  auto body = [&](int buf) {
    const float* xb = Xl + buf * 4096;
    const unsigned short* bb = Bl + buf * 12288;
    bf16x8 bfr[2][6];
#pragma unroll
    for (int ks = 0; ks < 2; ++ks)
#pragma unroll
      for (int n = 0; n < 6; ++n) {
        int col = colbase + 16 * n + r;
        bfr[ks][n] = *(const bf16x8*)&bb[col * 64 + (((ks * 4 + g) ^ (col & 7)) * 8)];
      }
#pragma unroll
    for (int ks = 0; ks < 2; ++ks) {
      int s0 = ks * 8 + 2 * g;
      f32x4 v0 = *(const f32x4*)&xb[rb + (((s0 & 8) | ((s0 & 7) ^ rx)) * 4)];
      f32x4 v1 = *(const f32x4*)&xb[rb + ((((s0 + 1) & 8) | (((s0 + 1) & 7) ^ rx)) * 4)];
      union { bf16x8 v; unsigned int u[4]; } af;
      af.u[0] = pack_bf2(v0.x, v0.y);
      af.u[1] = pack_bf2(v0.z, v0.w);
      af.u[2] = pack_bf2(v1.x, v1.y);
      af.u[3] = pack_bf2(v1.z, v1.w);
#pragma unroll
      for (int n = 0; n < 6; ++n)
        acc[n] = __builtin_amdgcn_mfma_f32_16x16x32_bf16(af.v, bfr[ks][n], acc[n], 0, 0, 0);
    }
  };

  // prologue: tiles 0,1 in flight (5 loads/thread each)
  stage(0, 0);
  stage(1, 1);

  for (int t = 0; t < 15; ++t) {
    WAITVM(5);                        // tile t landed; tile t+1's 5 stay in flight
    __builtin_amdgcn_s_barrier();     // also proves: all waves done with body(t-1)
    if (t + 2 < 16) stage(t + 2, (t + 2) % 3);  // overwrites body(t-1)'s buffer
    body(t % 3);
  }
  WAITVM(0);
  __builtin_amdgcn_s_barrier();
  body(0);                            // t=15 (15%3 == 0)

  // ---- epilogue: ALL outputs via LDS -> coalesced bf16x8 stores.
  // Overlays (all dead, barrier-protected):
  //   Kq [64][136] bf16 @16384..33792  (Xl buf1/2: last read t=13/t=14)
  //   Vt [64][65]  f32  @73728..90368  (Bl buf1:   last read t=13)
  // body(15) concurrently reads Xl buf0 (0..16384) + Bl buf0 (49152..73728):
  // disjoint from both overlay regions.
  unsigned short* Kq = (unsigned short*)(smem + 16384);
  float* Vt = (float*)(smem + 73728);
#pragma unroll
  for (int n = 0; n < 6; ++n) {
#pragma unroll
    for (int i = 0; i < 4; ++i) {
      int row = rowgrp * 16 + 4 * g + i;           // 0..63 within block
      int col = colbase + 16 * n + r;              // 0..191
      float val = acc[n][i];
      if (col < 128) {
        Kq[row * 136 + col] = f2bf(val);
      } else {
        Vt[(col - 128) * 65 + row] = val;
      }
    }
  }
  __syncthreads();
  {
    int row = tid >> 3, c8 = (tid & 7) * 8;        // 512 thr = 64 rows x 8 chunks
    *(bf16x8*)&kb[(size_t)(m0 + row) * HH + c8] = *(const bf16x8*)&Kq[row * 136 + c8];
    *(bf16x8*)&qb[(size_t)(m0 + row) * HH + c8] = *(const bf16x8*)&Kq[row * 136 + 64 + c8];
    union { bf16x8 v; unsigned short h[8]; } pk;
#pragma unroll
    for (int j = 0; j < 8; ++j) pk.h[j] = f2bf(Vt[row * 65 + c8 + j]);
    int b = m0 >> 12;
    int tt = (m0 & (TT - 1)) + c8;
    *(bf16x8*)&vt[(((size_t)b * HH + row) << 12) + tt] = pk.v;
  }
}

// ---------------- kernel 2: windowed flash attention, 64-row blocks
// Verbatim R10: 256 blocks x 512 threads, 8 waves = 4 q-quarters x 2
// kv-groups, 25-nat window -> nsteps == 1; block mapping matches proj's ->
// same-XCD L2 hits on Q/K/V.
__global__ __launch_bounds__(512, 4) void attn_kernel(
    const unsigned short* __restrict__ qb, const unsigned short* __restrict__ kb,
    const unsigned short* __restrict__ vt, const float* __restrict__ decayp,
    float* __restrict__ out) {
  extern __shared__ __align__(16) char smem[];
  unsigned short* Kl = (unsigned short*)smem;             // [2 tile][64][64] sw = 16KB
  unsigned short* Vl = (unsigned short*)(smem + 16384);   // [2 tile][64dim][64] sw = 16KB
  unsigned short* Pl = (unsigned short*)(smem + 32768);   // [8 waves][16][64] = 16KB
  float* Ol = (float*)(smem + 49152);                     // [64][68] f32 = 17408B
  float* Ml = (float*)(smem + 66560);                     // [64]
  float* Ll = (float*)(smem + 66816);                     // [64]

  const int tid = threadIdx.x;
  const int lane = tid & 63;
  const int w = tid >> 6;                  // 0..7
  const int r = lane & 15, g = lane >> 4;
  const int qh = w & 3;                    // q quarter (16 rows)
  const int kvg = w >> 2;                  // kv group == staged-tile index
  const int batch = blockIdx.x >> 6;
  const int mt = blockIdx.x & 63;          // own q/K tile within batch
  const int qbase0 = mt * 64;
  const int qw = qbase0 + qh * 16;
  const int qrow = qw + r;                 // this lane's q row

  const float decay = fabsf(decayp[0]);

  const unsigned short* qbb = qb + (size_t)batch * TT * HH;
  const unsigned short* kbb = kb + (size_t)batch * TT * HH;
  const unsigned short* vbb = vt + (size_t)batch * HH * TT;

  const unsigned short* qp = qbb + (size_t)qrow * HH;
  bf16x8 aq0 = *(const bf16x8*)(qp + 8 * g);        // dims 8g..8g+7
  bf16x8 aq1 = *(const bf16x8*)(qp + 32 + 8 * g);   // dims 32+8g..

  // device-side decay window (25 nats; dropped tokens >= 52 away -> bias
  // <= -26 nats; omitted/kept <= e^(14-26)/(1-e^-0.5) ~ 1.5e-5)
  int t0 = 0;
  if (decay > 1e-8f) {
    float wf = 25.f / decay;
    if (wf < (float)TT) {
      int W = (int)wf + 1;
      int lo = qbase0 - W;
      if (lo < 0) lo = 0;
      t0 = lo >> 6;
    }
  }
  const int t1 = mt;
  const int nsteps = (t1 - t0 + 2) >> 1;   // == 1 at decay=0.5

  // staging: 4 x 16B chunks/thread/step (2 K + 2 V), pre-swizzled source.
  const unsigned short* ksrc[2];
  const unsigned short* vsrc[2];
#pragma unroll
  for (int j = 0; j < 2; ++j) {
    int c = j * 512 + tid;                 // 0..1023 chunks (2 tiles)
    int th = c >> 9;                       // tile half 0/1
    int cc = c & 511;
    int row = cc >> 3, sl = cc & 7;
    ksrc[j] = kbb + (size_t)((t0 + th) * 64 + row) * HH + ((sl ^ (row & 7)) * 8);
    vsrc[j] = vbb + (size_t)row * TT + (t0 + th) * 64 + ((sl ^ (row & 7)) * 8);
  }

  auto stage = [&](int s) {
#pragma unroll
    for (int j = 0; j < 2; ++j) {
      gll16(ksrc[j] + (size_t)s * 8192, Kl + (j * 512 + w * 64) * 8);
      gll16(vsrc[j] + s * 128, Vl + (j * 512 + w * 64) * 8);
    }
  };

  float m = -1e30f, lsum = 0.f;
  f32x4 o[4];
#pragma unroll
  for (int n = 0; n < 4; ++n) { f32x4 z = {0.f, 0.f, 0.f, 0.f}; o[n] = z; }

  for (int s = 0; s < nsteps; ++s) {
    stage(s);
    WAITVM(0);
    __syncthreads();

    const int myt = t0 + 2 * s + kvg;
    if (myt <= t1) {
      const unsigned short* Kb = Kl + kvg * 4096;
      const unsigned short* Vb = Vl + kvg * 4096;
      const int kv0 = myt * 64;

      // S^T = K Q^T  (D: row kv = 16t+4g+i, col q = r)
      f32x4 sacc[4];
      __builtin_amdgcn_s_setprio(1);
#pragma unroll
      for (int t = 0; t < 4; ++t) {
        f32x4 z = {0.f, 0.f, 0.f, 0.f};
        int kvr = 16 * t + r;
        bf16x8 b0 = *(const bf16x8*)&Kb[kvr * 64 + ((g ^ (kvr & 7)) * 8)];
        bf16x8 b1 = *(const bf16x8*)&Kb[kvr * 64 + (((4 + g) ^ (kvr & 7)) * 8)];
        z = __builtin_amdgcn_mfma_f32_16x16x32_bf16(b0, aq0, z, 0, 0, 0);
        sacc[t] = __builtin_amdgcn_mfma_f32_16x16x32_bf16(b1, aq1, z, 0, 0, 0);
      }
      __builtin_amdgcn_s_setprio(0);

      // bias + causal mask + online softmax (lane-local q-row)
      float p[4][4];
      float rmax = -1e30f;
#pragma unroll
      for (int t = 0; t < 4; ++t)
#pragma unroll
        for (int i = 0; i < 4; ++i) {
          int kv = kv0 + 16 * t + 4 * g + i;
          float sv = sacc[t][i] * 0.125f + decay * (float)(kv - qrow);
          if (kv > qrow) sv = -1e30f;
          p[t][i] = sv;
          rmax = fmaxf(rmax, sv);
        }
      rmax = fmaxf(rmax, __shfl_xor(rmax, 16));
      rmax = fmaxf(rmax, __shfl_xor(rmax, 32));
      float mn = fmaxf(m, rmax);
      float al = __expf(m - mn);
      m = mn;
      float rs = 0.f;
#pragma unroll
      for (int t = 0; t < 4; ++t)
#pragma unroll
        for (int i = 0; i < 4; ++i) {
          float e = __expf(p[t][i] - mn);
          p[t][i] = e;
          rs += e;
        }
      rs += __shfl_xor(rs, 16);
      rs += __shfl_xor(rs, 32);
      lsum = lsum * al + rs;
#pragma unroll
      for (int n = 0; n < 4; ++n) {
        o[n][0] *= al; o[n][1] *= al; o[n][2] *= al; o[n][3] *= al;
      }

      // P[q=r][kv] bf16, 32B-slot XOR swizzle within the 128B row
      char* P = (char*)(Pl + w * 1024) + r * 128;
#pragma unroll
      for (int t = 0; t < 4; ++t) {
        uint2 uu;
        uu.x = pack_bf2(p[t][0], p[t][1]);
        uu.y = pack_bf2(p[t][2], p[t][3]);
        *(uint2*)(P + ((t ^ (r & 3)) * 32) + g * 8) = uu;
      }
      bf16x8 pb0 = *(const bf16x8*)(P + (((g >> 1) ^ (r & 3)) * 32) + (g & 1) * 16);
      bf16x8 pb1 = *(const bf16x8*)(P + ((((g >> 1) + 2) ^ (r & 3)) * 32) + (g & 1) * 16);

      // O^T += V^T . P^T   (A: row dim = 16n+r; D: row dim = 16n+4g+i, col q = r)
      __builtin_amdgcn_s_setprio(1);
#pragma unroll
      for (int n = 0; n < 4; ++n) {
        int dim = 16 * n + r;
        bf16x8 v0 = *(const bf16x8*)&Vb[dim * 64 + ((g ^ (dim & 7)) * 8)];
        bf16x8 v1 = *(const bf16x8*)&Vb[dim * 64 + (((4 + g) ^ (dim & 7)) * 8)];
        o[n] = __builtin_amdgcn_mfma_f32_16x16x32_bf16(v0, pb0, o[n], 0, 0, 0);
        o[n] = __builtin_amdgcn_mfma_f32_16x16x32_bf16(v1, pb1, o[n], 0, 0, 0);
      }
      __builtin_amdgcn_s_setprio(0);
    }
    __syncthreads();
  }

  // ---- merge the two kv-groups (flash combine), via padded LDS
  const int orow = qh * 16 + r;            // 0..63
  if (kvg == 1) {
    if (lane < 16) { Ml[orow] = m; Ll[orow] = lsum; }
#pragma unroll
    for (int n = 0; n < 4; ++n)
#pragma unroll
      for (int i = 0; i < 4; ++i)
        Ol[orow * 68 + 16 * n + 4 * g + i] = o[n][i];
  }
  __syncthreads();
  if (kvg == 0) {
    float m2 = Ml[orow], l2 = Ll[orow];
    float M = fmaxf(m, m2);
    float e1 = __expf(m - M), e2 = __expf(m2 - M);
    float inv = 1.f / (lsum * e1 + l2 * e2);
#pragma unroll
    for (int n = 0; n < 4; ++n)
#pragma unroll
      for (int i = 0; i < 4; ++i) {
        int d = 16 * n + 4 * g + i;
        Ol[orow * 68 + d] = (o[n][i] * e1 + Ol[orow * 68 + d] * e2) * inv;
      }
  }
  __syncthreads();

  // coalesced store: 64 rows x 64 dims f32
  float* ob = out + (size_t)batch * TT * HH + (size_t)qbase0 * HH;
#pragma unroll
  for (int j = 0; j < 2; ++j) {
    int c = j * 512 + tid;
    int row = c >> 4, q4 = (c & 15) * 4;
    f32x4 vv = *(const f32x4*)&Ol[row * 68 + q4];
    *(f32x4*)&ob[(size_t)row * HH + q4] = vv;
  }
}

extern "C" void kernel_launch(void* const* d_in, const int* in_sizes, int n_in,
                              void* d_out, int out_size, void* d_ws, size_t ws_size,
                              hipStream_t stream) {
  const float* x = (const float*)d_in[0];
  const float* Wk = (const float*)d_in[1];
  const float* Wq = (const float*)d_in[2];
  const float* Wv = (const float*)d_in[3];
  const float* decay = (const float*)d_in[4];
  float* out = (float*)d_out;

  unsigned short* kb = (unsigned short*)d_ws;          // [16384][64] bf16
  unsigned short* qbw = kb + (size_t)MTOT * HH;        // [16384][64] bf16
  unsigned short* vt = qbw + (size_t)MTOT * HH;        // [4][64][4096] bf16 (transposed)
  unsigned short* Wt = vt + (size_t)MTOT * HH;         // [192][1024] bf16

  prep_wt<<<dim3(48), dim3(256), 0, stream>>>(Wk, Wq, Wv, Wt);
  proj_kernel<<<dim3(256), dim3(512), 120 * 1024, stream>>>(x, Wt, kb, qbw, vt);
  attn_kernel<<<dim3(256), dim3(512), 67072, stream>>>(qbw, kb, vt, decay, out);
}

// Round 12
// 30.565 us; speedup vs baseline: 1.0141x; 1.0141x over previous
//
#include <hip/hip_runtime.h>

typedef short bf16x8 __attribute__((ext_vector_type(8)));
typedef float f32x4 __attribute__((ext_vector_type(4)));

#define TT 4096
#define CC 1024
#define HH 64
#define MTOT 16384   // B*T = 4*4096

static __device__ __forceinline__ unsigned short f2bf(float f) {
  unsigned int u = __float_as_uint(f);
  unsigned int r = (u + 0x7FFFu + ((u >> 16) & 1u)) >> 16;
  return (unsigned short)r;
}

// round-half-up f32 pair -> packed bf16x2 (1 add each + 1 perm)
static __device__ __forceinline__ unsigned int pack_bf2(float lo, float hi) {
  unsigned int ul = __float_as_uint(lo) + 0x8000u;
  unsigned int uh = __float_as_uint(hi) + 0x8000u;
  return __builtin_amdgcn_perm(uh, ul, 0x07060302u);  // [ul>>16, uh>>16]
}

typedef const __attribute__((address_space(1))) void gvoid;
typedef __attribute__((address_space(3))) void svoid;
static __device__ __forceinline__ void gll16(const void* g, void* l) {
  __builtin_amdgcn_global_load_lds((gvoid*)g, (svoid*)l, 16, 0, 0);
}

#define WAITVM(N) asm volatile("s_waitcnt vmcnt(" #N ")" ::: "memory")

// ---------------- kernel 0: W -> Wt[192][1024] bf16 (transposed, concat k|q|v)
__global__ void prep_wt(const float* __restrict__ Wk, const float* __restrict__ Wq,
                        const float* __restrict__ Wv, unsigned short* __restrict__ Wt) {
  __shared__ float T[64][65];
  const int mat = blockIdx.x >> 4;         // 0..2  (48 blocks)
  const int kt = blockIdx.x & 15;          // 0..15
  const float* src = (mat == 0) ? Wk : ((mat == 1) ? Wq : Wv);
#pragma unroll
  for (int i = 0; i < 4; ++i) {
    int c = i * 256 + threadIdx.x;         // 0..1023 f32x4 chunks
    int row = c >> 4, col = (c & 15) * 4;
    f32x4 v = *(const f32x4*)&src[(size_t)(kt * 64 + row) * HH + col];
    T[col + 0][row] = v[0];
    T[col + 1][row] = v[1];
    T[col + 2][row] = v[2];
    T[col + 3][row] = v[3];
  }
  __syncthreads();
#pragma unroll
  for (int i = 0; i < 2; ++i) {
    int c2 = i * 256 + threadIdx.x;        // 0..511 bf16x8 chunks
    int row = c2 >> 3, k0 = (c2 & 7) * 8;
    union { bf16x8 v; unsigned short h[8]; } pk;
#pragma unroll
    for (int j = 0; j < 8; ++j) pk.h[j] = f2bf(T[row][k0 + j]);
    *(bf16x8*)&Wt[(size_t)(mat * 64 + row) * CC + kt * 64 + k0] = pk.v;
  }
}

// ---------------- kernel 1: projections, DMA-only K-loop GEMM, BM=64
// R3/R8 structure: (512,2), 48-64 VGPR fit, 1 blk/CU, 3 LDS bufs, single
// barrier per K-tile, counted vmcnt(5). Verified local optimum (R2/R6/R9
// structural alternatives all regressed; R11 epilogue coalescing neutral-neg).
__global__ __launch_bounds__(512, 2) void proj_kernel(
    const float* __restrict__ x, const unsigned short* __restrict__ Wt,
    unsigned short* __restrict__ kb, unsigned short* __restrict__ qb,
    unsigned short* __restrict__ vt) {
  extern __shared__ __align__(16) char smem[];
  float* Xl = (float*)smem;                                   // [3][64*64] f32 = 48KB
  unsigned short* Bl = (unsigned short*)(smem + 49152);       // [3][192*64] bf16 = 72KB

  const int tid = threadIdx.x;
  const int lane = tid & 63;
  const int w = tid >> 6;                  // 0..7
  const int r = lane & 15, g = lane >> 4;
  const int rowgrp = w >> 1;               // 0..3 -> rows rowgrp*16..+15
  const int colbase = (w & 1) * 96;        // 0 or 96
  const int m0 = blockIdx.x * 64;

  // ---- staging sources (5 x 16B chunks per thread per tile), pre-swizzled
  const float* xsrcs[2];
#pragma unroll
  for (int j = 0; j < 2; ++j) {
    int c = j * 512 + tid;
    int row = c >> 4, s = c & 15;
    xsrcs[j] = x + (size_t)(m0 + row) * CC + (((s & 8) | ((s & 7) ^ (row & 7))) * 4);
  }
  const unsigned short* bsrcs[3];
#pragma unroll
  for (int j = 0; j < 3; ++j) {
    int cb = j * 512 + tid;
    int row = cb >> 3, s = cb & 7;
    bsrcs[j] = Wt + (size_t)row * CC + ((s ^ (row & 7)) * 8);
  }

  f32x4 acc[6];
#pragma unroll
  for (int n = 0; n < 6; ++n) { f32x4 z = {0.f, 0.f, 0.f, 0.f}; acc[n] = z; }

  auto stage = [&](int t, int buf) {
    float* xb = Xl + buf * 4096;
    unsigned short* bb = Bl + buf * 12288;
#pragma unroll
    for (int j = 0; j < 2; ++j)
      gll16(xsrcs[j] + t * 64, xb + (j * 512 + w * 64) * 4);
#pragma unroll
    for (int j = 0; j < 3; ++j)
      gll16(bsrcs[j] + t * 64, bb + (size_t)(j * 512 + w * 64) * 8);
  };

  const int rr = rowgrp * 16 + r;
  const int rb = rr * 64;
  const int rx = rr & 7;

  auto body = [&](int buf) {
    const float* xb = Xl + buf * 4096;
    const unsigned short* bb = Bl + buf * 12288;
    bf16x8 bfr[2][6];
#pragma unroll
    for (int ks = 0; ks < 2; ++ks)
#pragma unroll
      for (int n = 0; n < 6; ++n) {
        int col = colbase + 16 * n + r;
        bfr[ks][n] = *(const bf16x8*)&bb[col * 64 + (((ks * 4 + g) ^ (col & 7)) * 8)];
      }
#pragma unroll
    for (int ks = 0; ks < 2; ++ks) {
      int s0 = ks * 8 + 2 * g;
      f32x4 v0 = *(const f32x4*)&xb[rb + (((s0 & 8) | ((s0 & 7) ^ rx)) * 4)];
      f32x4 v1 = *(const f32x4*)&xb[rb + ((((s0 + 1) & 8) | (((s0 + 1) & 7) ^ rx)) * 4)];
      union { bf16x8 v; unsigned int u[4]; } af;
      af.u[0] = pack_bf2(v0.x, v0.y);
      af.u[1] = pack_bf2(v0.z, v0.w);
      af.u[2] = pack_bf2(v1.x, v1.y);
      af.u[3] = pack_bf2(v1.z, v1.w);
#pragma unroll
      for (int n = 0; n < 6; ++n)
        acc[n] = __builtin_amdgcn_mfma_f32_16x16x32_bf16(af.v, bfr[ks][n], acc[n], 0, 0, 0);
    }
  };

  // prologue: tiles 0,1 in flight (5 loads/thread each)
  stage(0, 0);
  stage(1, 1);

  for (int t = 0; t < 15; ++t) {
    WAITVM(5);                        // tile t landed; tile t+1's 5 stay in flight
    __builtin_amdgcn_s_barrier();     // also proves: all waves done with body(t-1)
    if (t + 2 < 16) stage(t + 2, (t + 2) % 3);  // overwrites body(t-1)'s buffer
    body(t % 3);
  }
  WAITVM(0);
  __builtin_amdgcn_s_barrier();
  body(0);                            // t=15 (15%3 == 0)

  // ---- epilogue: k/q scalar scatter; V -> padded LDS -> coalesced stores
  float* Vt = (float*)(smem + 73728);  // [64][65] f32, in Bl buf-1 region (dead)
#pragma unroll
  for (int n = 0; n < 6; ++n) {
#pragma unroll
    for (int i = 0; i < 4; ++i) {
      int row = rowgrp * 16 + 4 * g + i;           // 0..63 within block
      int col = colbase + 16 * n + r;              // 0..191
      float val = acc[n][i];
      if (col < 64) {
        kb[(size_t)(m0 + row) * HH + col] = f2bf(val);
      } else if (col < 128) {
        qb[(size_t)(m0 + row) * HH + (col - 64)] = f2bf(val);
      } else {
        Vt[(col - 128) * 65 + row] = val;
      }
    }
  }
  __syncthreads();
  {
    int dim = tid >> 3, t8 = (tid & 7) * 8;        // 512 threads = 64 dims x 8 chunks
    union { bf16x8 v; unsigned short h[8]; } pk;
#pragma unroll
    for (int j = 0; j < 8; ++j) pk.h[j] = f2bf(Vt[dim * 65 + t8 + j]);
    int b = m0 >> 12;
    int tt = (m0 & (TT - 1)) + t8;
    *(bf16x8*)&vt[(((size_t)b * HH + dim) << 12) + tt] = pk.v;
  }
}

// ---------------- kernel 2: windowed flash attention, 64-row blocks
// R10: 256 blocks x 512 threads, 8 waves = 4 q-quarters x 2 kv-groups,
// 25-nat window -> nsteps == 1; block mapping matches proj's -> same-XCD
// L2 hits on Q/K/V.
__global__ __launch_bounds__(512, 4) void attn_kernel(
    const unsigned short* __restrict__ qb, const unsigned short* __restrict__ kb,
    const unsigned short* __restrict__ vt, const float* __restrict__ decayp,
    float* __restrict__ out) {
  extern __shared__ __align__(16) char smem[];
  unsigned short* Kl = (unsigned short*)smem;             // [2 tile][64][64] sw = 16KB
  unsigned short* Vl = (unsigned short*)(smem + 16384);   // [2 tile][64dim][64] sw = 16KB
  unsigned short* Pl = (unsigned short*)(smem + 32768);   // [8 waves][16][64] = 16KB
  float* Ol = (float*)(smem + 49152);                     // [64][68] f32 = 17408B
  float* Ml = (float*)(smem + 66560);                     // [64]
  float* Ll = (float*)(smem + 66816);                     // [64]

  const int tid = threadIdx.x;
  const int lane = tid & 63;
  const int w = tid >> 6;                  // 0..7
  const int r = lane & 15, g = lane >> 4;
  const int qh = w & 3;                    // q quarter (16 rows)
  const int kvg = w >> 2;                  // kv group == staged-tile index
  const int batch = blockIdx.x >> 6;
  const int mt = blockIdx.x & 63;          // own q/K tile within batch
  const int qbase0 = mt * 64;
  const int qw = qbase0 + qh * 16;
  const int qrow = qw + r;                 // this lane's q row

  const float decay = fabsf(decayp[0]);

  const unsigned short* qbb = qb + (size_t)batch * TT * HH;
  const unsigned short* kbb = kb + (size_t)batch * TT * HH;
  const unsigned short* vbb = vt + (size_t)batch * HH * TT;

  const unsigned short* qp = qbb + (size_t)qrow * HH;
  bf16x8 aq0 = *(const bf16x8*)(qp + 8 * g);        // dims 8g..8g+7
  bf16x8 aq1 = *(const bf16x8*)(qp + 32 + 8 * g);   // dims 32+8g..

  // device-side decay window (25 nats; dropped tokens >= 52 away -> bias
  // <= -26 nats; omitted/kept <= e^(14-26)/(1-e^-0.5) ~ 1.5e-5)
  int t0 = 0;
  if (decay > 1e-8f) {
    float wf = 25.f / decay;
    if (wf < (float)TT) {
      int W = (int)wf + 1;
      int lo = qbase0 - W;
      if (lo < 0) lo = 0;
      t0 = lo >> 6;
    }
  }
  const int t1 = mt;
  const int nsteps = (t1 - t0 + 2) >> 1;   // == 1 at decay=0.5

  // staging: 4 x 16B chunks/thread/step (2 K + 2 V), pre-swizzled source.
  const unsigned short* ksrc[2];
  const unsigned short* vsrc[2];
#pragma unroll
  for (int j = 0; j < 2; ++j) {
    int c = j * 512 + tid;                 // 0..1023 chunks (2 tiles)
    int th = c >> 9;                       // tile half 0/1
    int cc = c & 511;
    int row = cc >> 3, sl = cc & 7;
    ksrc[j] = kbb + (size_t)((t0 + th) * 64 + row) * HH + ((sl ^ (row & 7)) * 8);
    vsrc[j] = vbb + (size_t)row * TT + (t0 + th) * 64 + ((sl ^ (row & 7)) * 8);
  }

  auto stage = [&](int s) {
#pragma unroll
    for (int j = 0; j < 2; ++j) {
      gll16(ksrc[j] + (size_t)s * 8192, Kl + (j * 512 + w * 64) * 8);
      gll16(vsrc[j] + s * 128, Vl + (j * 512 + w * 64) * 8);
    }
  };

  float m = -1e30f, lsum = 0.f;
  f32x4 o[4];
#pragma unroll
  for (int n = 0; n < 4; ++n) { f32x4 z = {0.f, 0.f, 0.f, 0.f}; o[n] = z; }

  for (int s = 0; s < nsteps; ++s) {
    stage(s);
    WAITVM(0);
    __syncthreads();

    const int myt = t0 + 2 * s + kvg;
    if (myt <= t1) {
      const unsigned short* Kb = Kl + kvg * 4096;
      const unsigned short* Vb = Vl + kvg * 4096;
      const int kv0 = myt * 64;

      // S^T = K Q^T  (D: row kv = 16t+4g+i, col q = r)
      f32x4 sacc[4];
      __builtin_amdgcn_s_setprio(1);
#pragma unroll
      for (int t = 0; t < 4; ++t) {
        f32x4 z = {0.f, 0.f, 0.f, 0.f};
        int kvr = 16 * t + r;
        bf16x8 b0 = *(const bf16x8*)&Kb[kvr * 64 + ((g ^ (kvr & 7)) * 8)];
        bf16x8 b1 = *(const bf16x8*)&Kb[kvr * 64 + (((4 + g) ^ (kvr & 7)) * 8)];
        z = __builtin_amdgcn_mfma_f32_16x16x32_bf16(b0, aq0, z, 0, 0, 0);
        sacc[t] = __builtin_amdgcn_mfma_f32_16x16x32_bf16(b1, aq1, z, 0, 0, 0);
      }
      __builtin_amdgcn_s_setprio(0);

      // bias + causal mask + online softmax (lane-local q-row)
      float p[4][4];
      float rmax = -1e30f;
#pragma unroll
      for (int t = 0; t < 4; ++t)
#pragma unroll
        for (int i = 0; i < 4; ++i) {
          int kv = kv0 + 16 * t + 4 * g + i;
          float sv = sacc[t][i] * 0.125f + decay * (float)(kv - qrow);
          if (kv > qrow) sv = -1e30f;
          p[t][i] = sv;
          rmax = fmaxf(rmax, sv);
        }
      rmax = fmaxf(rmax, __shfl_xor(rmax, 16));
      rmax = fmaxf(rmax, __shfl_xor(rmax, 32));
      float mn = fmaxf(m, rmax);
      float al = __expf(m - mn);
      m = mn;
      float rs = 0.f;
#pragma unroll
      for (int t = 0; t < 4; ++t)
#pragma unroll
        for (int i = 0; i < 4; ++i) {
          float e = __expf(p[t][i] - mn);
          p[t][i] = e;
          rs += e;
        }
      rs += __shfl_xor(rs, 16);
      rs += __shfl_xor(rs, 32);
      lsum = lsum * al + rs;
#pragma unroll
      for (int n = 0; n < 4; ++n) {
        o[n][0] *= al; o[n][1] *= al; o[n][2] *= al; o[n][3] *= al;
      }

      // P[q=r][kv] bf16, 32B-slot XOR swizzle within the 128B row
      char* P = (char*)(Pl + w * 1024) + r * 128;
#pragma unroll
      for (int t = 0; t < 4; ++t) {
        uint2 uu;
        uu.x = pack_bf2(p[t][0], p[t][1]);
        uu.y = pack_bf2(p[t][2], p[t][3]);
        *(uint2*)(P + ((t ^ (r & 3)) * 32) + g * 8) = uu;
      }
      bf16x8 pb0 = *(const bf16x8*)(P + (((g >> 1) ^ (r & 3)) * 32) + (g & 1) * 16);
      bf16x8 pb1 = *(const bf16x8*)(P + ((((g >> 1) + 2) ^ (r & 3)) * 32) + (g & 1) * 16);

      // O^T += V^T . P^T   (A: row dim = 16n+r; D: row dim = 16n+4g+i, col q = r)
      __builtin_amdgcn_s_setprio(1);
#pragma unroll
      for (int n = 0; n < 4; ++n) {
        int dim = 16 * n + r;
        bf16x8 v0 = *(const bf16x8*)&Vb[dim * 64 + ((g ^ (dim & 7)) * 8)];
        bf16x8 v1 = *(const bf16x8*)&Vb[dim * 64 + (((4 + g) ^ (dim & 7)) * 8)];
        o[n] = __builtin_amdgcn_mfma_f32_16x16x32_bf16(v0, pb0, o[n], 0, 0, 0);
        o[n] = __builtin_amdgcn_mfma_f32_16x16x32_bf16(v1, pb1, o[n], 0, 0, 0);
      }
      __builtin_amdgcn_s_setprio(0);
    }
    __syncthreads();
  }

  // ---- merge the two kv-groups (flash combine), via padded LDS
  const int orow = qh * 16 + r;            // 0..63
  if (kvg == 1) {
    if (lane < 16) { Ml[orow] = m; Ll[orow] = lsum; }
#pragma unroll
    for (int n = 0; n < 4; ++n)
#pragma unroll
      for (int i = 0; i < 4; ++i)
        Ol[orow * 68 + 16 * n + 4 * g + i] = o[n][i];
  }
  __syncthreads();
  if (kvg == 0) {
    float m2 = Ml[orow], l2 = Ll[orow];
    float M = fmaxf(m, m2);
    float e1 = __expf(m - M), e2 = __expf(m2 - M);
    float inv = 1.f / (lsum * e1 + l2 * e2);
#pragma unroll
    for (int n = 0; n < 4; ++n)
#pragma unroll
      for (int i = 0; i < 4; ++i) {
        int d = 16 * n + 4 * g + i;
        Ol[orow * 68 + d] = (o[n][i] * e1 + Ol[orow * 68 + d] * e2) * inv;
      }
  }
  __syncthreads();

  // coalesced store: 64 rows x 64 dims f32
  float* ob = out + (size_t)batch * TT * HH + (size_t)qbase0 * HH;
#pragma unroll
  for (int j = 0; j < 2; ++j) {
    int c = j * 512 + tid;
    int row = c >> 4, q4 = (c & 15) * 4;
    f32x4 vv = *(const f32x4*)&Ol[row * 68 + q4];
    *(f32x4*)&ob[(size_t)row * HH + q4] = vv;
  }
}

extern "C" void kernel_launch(void* const* d_in, const int* in_sizes, int n_in,
                              void* d_out, int out_size, void* d_ws, size_t ws_size,
                              hipStream_t stream) {
  const float* x = (const float*)d_in[0];
  const float* Wk = (const float*)d_in[1];
  const float* Wq = (const float*)d_in[2];
  const float* Wv = (const float*)d_in[3];
  const float* decay = (const float*)d_in[4];
  float* out = (float*)d_out;

  unsigned short* kb = (unsigned short*)d_ws;          // [16384][64] bf16
  unsigned short* qbw = kb + (size_t)MTOT * HH;        // [16384][64] bf16
  unsigned short* vt = qbw + (size_t)MTOT * HH;        // [4][64][4096] bf16 (transposed)
  unsigned short* Wt = vt + (size_t)MTOT * HH;         // [192][1024] bf16

  prep_wt<<<dim3(48), dim3(256), 0, stream>>>(Wk, Wq, Wv, Wt);
  proj_kernel<<<dim3(256), dim3(512), 120 * 1024, stream>>>(x, Wt, kb, qbw, vt);
  attn_kernel<<<dim3(256), dim3(512), 67072, stream>>>(qbw, kb, vt, decay, out);
}